// Round 7
// baseline (11080.849 us; speedup 1.0000x reference)
//
#include <hip/hip_runtime.h>
#include <cstddef>

#define NN 100000
#define NE 400000
#define NG 256
#define HIDC 256
#define EPSN 1e-5f

typedef unsigned short bfu;  // bf16 bits

__device__ __forceinline__ float bf2f(bfu b) {
    union { unsigned int u; float f; } v; v.u = ((unsigned int)b) << 16; return v.f;
}
__device__ __forceinline__ bfu f2bf(float f) {
    union { float f; unsigned int u; } v; v.f = f;
    unsigned int r = v.u + 0x7FFFu + ((v.u >> 16) & 1u);
    return (bfu)(r >> 16);
}
// dual-dtype helpers: bf=1 -> bf16 storage, bf=0 -> fp32 storage
__device__ __forceinline__ float4 ld4(const void* p, size_t i, int bf) {
    if (bf) {
        ushort4 u = *(const ushort4*)((const bfu*)p + i);
        return make_float4(bf2f(u.x), bf2f(u.y), bf2f(u.z), bf2f(u.w));
    }
    return *(const float4*)((const float*)p + i);
}
__device__ __forceinline__ float ld1(const void* p, size_t i, int bf) {
    return bf ? bf2f(((const bfu*)p)[i]) : ((const float*)p)[i];
}
__device__ __forceinline__ void st1(void* p, size_t i, float v, int bf) {
    if (bf) ((bfu*)p)[i] = f2bf(v); else ((float*)p)[i] = v;
}

// ---------------- dtype detect: norm_gamma == ones ----------------
__global__ void k_detect(const unsigned int* __restrict__ g, int* __restrict__ flag) {
    if (threadIdx.x == 0)
        flag[0] = (g[0] == 0x3F800000u) ? 0 : 1;  // fp32 ones : bf16 ones (0x3F803F80)
}

// ---------------- telemetry ----------------
__global__ void k_sent(void* __restrict__ out, const int* __restrict__ dtf) {
    int i = threadIdx.x;  // 256 threads
    st1(out, i, 42.0f, *dtf);
}
__global__ void k_mark(void* __restrict__ out, const int* __restrict__ dtf, float v) {
    if (threadIdx.x == 0) st1(out, 0, v, *dtf);
}

// ---------------- graph starts (batch sorted) ----------------
__global__ void k_starts(const int* __restrict__ batch, int* __restrict__ starts) {
    int g = threadIdx.x;
    if (g > NG) return;
    if (g == NG) { starts[NG] = NN; return; }
    int lo = 0, hi = NN;
    while (lo < hi) { int mid = (lo + hi) >> 1; if (batch[mid] < g) lo = mid + 1; else hi = mid; }
    starts[g] = lo;
}

// ---------------- zero fill ----------------
__global__ void k_zero(float* __restrict__ p, int n4) {
    int i = blockIdx.x * blockDim.x + threadIdx.x;
    if (i < n4) ((float4*)p)[i] = make_float4(0.f, 0.f, 0.f, 0.f);
}

// ---------------- node embedding gather: h_bf16 <- node_emb_W[x] ----------------
__global__ void k_embed(const int* __restrict__ x, const void* __restrict__ W,
                        bfu* __restrict__ h, const int* __restrict__ dtf) {
    int tid = blockIdx.x * blockDim.x + threadIdx.x;
    if (tid >= NN * 64) return;
    int bf = *dtf;
    int n = tid >> 6, q = (tid & 63) << 2;
    int xv = x[n]; if ((unsigned)xv >= 8u) xv = 0;
    float4 v = ld4(W, (size_t)xv * HIDC + q, bf);
    ushort4 o; o.x = f2bf(v.x); o.y = f2bf(v.y); o.z = f2bf(v.z); o.w = f2bf(v.w);
    *(ushort4*)(h + (size_t)n * HIDC + q) = o;
}

// ---------------- scatter: agg[dst] += relu(h[src] + e), edges [e0, e0+ecnt) ------
__global__ void k_scatter(const bfu* __restrict__ h, const bfu* __restrict__ e,
                          const int* __restrict__ ei, float* __restrict__ agg,
                          int e0, int ecnt) {
    int tid = blockIdx.x * blockDim.x + threadIdx.x;
    if (tid >= ecnt * 64) return;
    int eid = tid >> 6, q = (tid & 63) << 2;
    int ge = e0 + eid;
    int s = ei[ge], d = ei[NE + ge];
    if ((unsigned)s >= (unsigned)NN || (unsigned)d >= (unsigned)NN) return;
    ushort4 hu = *(const ushort4*)(h + (size_t)s * HIDC + q);
    ushort4 eu = *(const ushort4*)(e + (size_t)eid * HIDC + q);
    float4 m;
    m.x = fmaxf(bf2f(hu.x) + bf2f(eu.x), 0.f);
    m.y = fmaxf(bf2f(hu.y) + bf2f(eu.y), 0.f);
    m.z = fmaxf(bf2f(hu.z) + bf2f(eu.z), 0.f);
    m.w = fmaxf(bf2f(hu.w) + bf2f(eu.w), 0.f);
    float* ap = agg + (size_t)d * HIDC + q;
    atomicAdd(ap + 0, m.x); atomicAdd(ap + 1, m.y);
    atomicAdd(ap + 2, m.z); atomicAdd(ap + 3, m.w);
}

// ---------------- tiled GEMM: C_bf16[M x 256] = A @ W + bias ----------------
#define BM 64
#define BN 64
#define BK 32

__global__ __launch_bounds__(256)
void k_gemm(const bfu* __restrict__ A, const float* __restrict__ A2,
            const void* __restrict__ attrs, long atOff,
            const void* __restrict__ Wemb, const void* __restrict__ bemb,
            const void* __restrict__ eps, int epsIdx,
            const void* __restrict__ W, long wOff,
            const void* __restrict__ bias, long bOff,
            const void* __restrict__ scalep, bfu* __restrict__ C, int M,
            int amode, int relu, int scale, const int* __restrict__ dtf) {
    __shared__ float As[BM][BK + 1];
    __shared__ float Ws[BK][BN];
    const int bf = *dtf;
    const int tid = threadIdx.x;
    const int m0 = blockIdx.x * BM;
    const int n0 = blockIdx.y * BN;
    const int rowb = (tid >> 4) * 4;
    const int colb = (tid & 15) * 4;
    float acc[4][4] = {};
    float epsv = 0.f;
    if (amode == 2) epsv = 1.0f + ld1(eps, epsIdx, bf);

    for (int k0 = 0; k0 < 256; k0 += BK) {
#pragma unroll
        for (int t = 0; t < 2; t++) {
            int f4 = tid + t * 256;
            int ar = f4 >> 3;
            int ak = (f4 & 7) << 2;
            int gm = m0 + ar;
            float4 v = make_float4(0.f, 0.f, 0.f, 0.f);
            if (gm < M) {
                if (amode == 0) {
                    ushort4 uv = *(const ushort4*)(A + (size_t)gm * HIDC + k0 + ak);
                    v = make_float4(bf2f(uv.x), bf2f(uv.y), bf2f(uv.z), bf2f(uv.w));
                } else if (amode == 2) {
                    ushort4 hu = *(const ushort4*)(A + (size_t)gm * HIDC + k0 + ak);
                    float4 av = *(const float4*)(A2 + (size_t)gm * HIDC + k0 + ak);
                    v.x = epsv * bf2f(hu.x) + av.x; v.y = epsv * bf2f(hu.y) + av.y;
                    v.z = epsv * bf2f(hu.z) + av.z; v.w = epsv * bf2f(hu.w) + av.w;
                } else {
                    float4 at = ld4(attrs, (size_t)atOff + (size_t)gm * 4, bf);
                    float a[4] = { at.x, at.y, at.z, at.w };
                    v = ld4(bemb, k0 + ak, bf);
#pragma unroll
                    for (int j = 0; j < 4; j++) {
                        float4 wv = ld4(Wemb, (size_t)j * HIDC + k0 + ak, bf);
                        v.x += a[j] * wv.x; v.y += a[j] * wv.y;
                        v.z += a[j] * wv.z; v.w += a[j] * wv.w;
                    }
                }
            }
            As[ar][ak + 0] = v.x; As[ar][ak + 1] = v.y;
            As[ar][ak + 2] = v.z; As[ar][ak + 3] = v.w;
        }
#pragma unroll
        for (int t = 0; t < 2; t++) {
            int f4 = tid + t * 256;
            int wr = f4 >> 4;
            int wn = (f4 & 15) << 2;
            *(float4*)(&Ws[wr][wn]) =
                ld4(W, (size_t)wOff + (size_t)(k0 + wr) * HIDC + n0 + wn, bf);
        }
        __syncthreads();
#pragma unroll
        for (int kk = 0; kk < BK; ++kk) {
            float a0 = As[rowb + 0][kk], a1 = As[rowb + 1][kk];
            float a2 = As[rowb + 2][kk], a3 = As[rowb + 3][kk];
            float4 b = *(const float4*)(&Ws[kk][colb]);
            acc[0][0] += a0 * b.x; acc[0][1] += a0 * b.y; acc[0][2] += a0 * b.z; acc[0][3] += a0 * b.w;
            acc[1][0] += a1 * b.x; acc[1][1] += a1 * b.y; acc[1][2] += a1 * b.z; acc[1][3] += a1 * b.w;
            acc[2][0] += a2 * b.x; acc[2][1] += a2 * b.y; acc[2][2] += a2 * b.z; acc[2][3] += a2 * b.w;
            acc[3][0] += a3 * b.x; acc[3][1] += a3 * b.y; acc[3][2] += a3 * b.z; acc[3][3] += a3 * b.w;
        }
        __syncthreads();
    }

    float4 bv = ld4(bias, (size_t)bOff + n0 + colb, bf);
#pragma unroll
    for (int i = 0; i < 4; i++) {
        int gm = m0 + rowb + i;
        if (gm >= M) continue;
        float4 o;
        o.x = acc[i][0] + bv.x; o.y = acc[i][1] + bv.y;
        o.z = acc[i][2] + bv.z; o.w = acc[i][3] + bv.w;
        if (relu) {
            o.x = fmaxf(o.x, 0.f); o.y = fmaxf(o.y, 0.f);
            o.z = fmaxf(o.z, 0.f); o.w = fmaxf(o.w, 0.f);
        }
        if (scale) {
            if (ld1(attrs, (size_t)atOff + (size_t)gm * 4 + 1, bf) > 0.f) {
                float sc = ld1(scalep, 0, bf);
                o.x *= sc; o.y *= sc; o.z *= sc; o.w *= sc;
            }
        }
        ushort4 ov; ov.x = f2bf(o.x); ov.y = f2bf(o.y); ov.z = f2bf(o.z); ov.w = f2bf(o.w);
        *(ushort4*)(C + (size_t)gm * HIDC + n0 + colb) = ov;
    }
}

// ---------------- GraphNorm stats ----------------
__global__ void k_stats(const bfu* __restrict__ h, const int* __restrict__ starts,
                        const void* __restrict__ alpha, long aOff,
                        float* __restrict__ gmean, float* __restrict__ gvar,
                        const int* __restrict__ dtf) {
    int bf = *dtf;
    int g = blockIdx.x, c = threadIdx.x;
    int s = starts[g], t = starts[g + 1];
    float sum = 0.f, sum2 = 0.f;
    for (int n = s; n < t; ++n) {
        float v = bf2f(h[(size_t)n * HIDC + c]);
        sum += v; sum2 += v * v;
    }
    int cn = t - s; if (cn < 1) cn = 1;
    float cnt = (float)cn;
    float m = sum / cnt;
    float a = ld1(alpha, (size_t)aOff + c, bf);
    float var = sum2 / cnt - (2.f * a - a * a) * m * m;
    gmean[g * HIDC + c] = m;
    gvar[g * HIDC + c] = fmaxf(var, 0.f);
}

// ---------------- GraphNorm apply ----------------
__global__ void k_norm(bfu* __restrict__ h, const int* __restrict__ batch,
                       const float* __restrict__ gmean, const float* __restrict__ gvar,
                       const void* __restrict__ gamma, const void* __restrict__ beta,
                       const void* __restrict__ alpha, long pOff,
                       const int* __restrict__ dtf) {
    int tid = blockIdx.x * blockDim.x + threadIdx.x;
    if (tid >= NN * 64) return;
    int bf = *dtf;
    int n = tid >> 6, q = (tid & 63) << 2;
    int g = batch[n]; if ((unsigned)g >= (unsigned)NG) g = 0;
    ushort4 hu = *(ushort4*)(h + (size_t)n * HIDC + q);
    const float4 mv = *(const float4*)(gmean + g * HIDC + q);
    const float4 vv = *(const float4*)(gvar + g * HIDC + q);
    float4 ga = ld4(gamma, (size_t)pOff + q, bf);
    float4 be = ld4(beta, (size_t)pOff + q, bf);
    float4 al = ld4(alpha, (size_t)pOff + q, bf);
    float4 v;
    v.x = ga.x * (bf2f(hu.x) - al.x * mv.x) * rsqrtf(vv.x + EPSN) + be.x;
    v.y = ga.y * (bf2f(hu.y) - al.y * mv.y) * rsqrtf(vv.y + EPSN) + be.y;
    v.z = ga.z * (bf2f(hu.z) - al.z * mv.z) * rsqrtf(vv.z + EPSN) + be.z;
    v.w = ga.w * (bf2f(hu.w) - al.w * mv.w) * rsqrtf(vv.w + EPSN) + be.w;
    ushort4 ov; ov.x = f2bf(v.x); ov.y = f2bf(v.y); ov.z = f2bf(v.z); ov.w = f2bf(v.w);
    *(ushort4*)(h + (size_t)n * HIDC + q) = ov;
}

// ---------------- global mean pool ----------------
__global__ void k_pool(const bfu* __restrict__ h, const int* __restrict__ starts,
                       float* __restrict__ g) {
    int gb = blockIdx.x, c = threadIdx.x;
    int s = starts[gb], t = starts[gb + 1];
    float sum = 0.f;
    for (int n = s; n < t; ++n) sum += bf2f(h[(size_t)n * HIDC + c]);
    int cn = t - s; if (cn < 1) cn = 1;
    g[gb * HIDC + c] = sum / (float)cn;
}

// ---------------- head MLP (adaptive out; NaN-at-acc telemetry -> 999) ----------------
__global__ void k_head(const float* __restrict__ g, const void* __restrict__ bio,
                       const void* __restrict__ W1, const void* __restrict__ b1,
                       const void* __restrict__ W2, const void* __restrict__ b2,
                       void* __restrict__ out, const int* __restrict__ dtf) {
    __shared__ float comb[768];
    __shared__ float red[256];
    __shared__ int nanf;
    int bf = *dtf;
    int gb = blockIdx.x, t = threadIdx.x;
    if (t == 0) nanf = 0;
    comb[t] = g[gb * HIDC + t];
    comb[256 + t] = ld1(bio, t, bf);
    comb[512 + t] = ld1(bio, 256 + t, bf);
    __syncthreads();
    float acc = ld1(b1, t, bf);
    for (int k = 0; k < 768; ++k) acc += comb[k] * ld1(W1, (size_t)k * HIDC + t, bf);
    if (isnan(acc) || isinf(acc)) nanf = 1;
    float hid = fmaxf(acc, 0.f);
    red[t] = hid * ld1(W2, t, bf);
    __syncthreads();
    for (int off = 128; off > 0; off >>= 1) {
        if (t < off) red[t] += red[t + off];
        __syncthreads();
    }
    if (t == 0) {
        float r = red[0] + ld1(b2, 0, bf);
        if (nanf || isnan(r)) r = 999.0f;  // telemetry: non-finite upstream
        st1(out, gb, r, bf);
    }
}

extern "C" void kernel_launch(void* const* d_in, const int* in_sizes, int n_in,
                              void* d_out, int out_size, void* d_ws, size_t ws_size,
                              hipStream_t stream) {
    const int* x = (const int*)d_in[0];
    const int* ei = (const int*)d_in[1];
    const void* eattr = d_in[2];
    const int* batch = (const int*)d_in[3];
    const void* node_emb_W = d_in[4];
    const void* edge_emb_W = d_in[5];
    const void* edge_emb_b = d_in[6];
    const void* emlp_W1 = d_in[7];
    const void* emlp_b1 = d_in[8];
    const void* emlp_W2 = d_in[9];
    const void* emlp_b2 = d_in[10];
    const void* struct_scale = d_in[11];
    const void* conv_W1 = d_in[12];
    const void* conv_b1 = d_in[13];
    const void* conv_W2 = d_in[14];
    const void* conv_b2 = d_in[15];
    const void* conv_eps = d_in[16];
    const void* ngamma = d_in[17];
    const void* nbeta = d_in[18];
    const void* nalpha = d_in[19];
    const void* mean_bio = d_in[20];
    const void* head_W1 = d_in[21];
    const void* head_b1 = d_in[22];
    const void* head_W2 = d_in[23];
    const void* head_b2 = d_in[24];
    (void)in_sizes; (void)n_in; (void)out_size; (void)ws_size;

    // Workspace (205.6 MB):
    //   [0,      51.2M)  h bf16       100k x 256
    //   [51.2M, 153.6M)  agg fp32     100k x 256
    //   [153.6M,179.2M)  e chunk bf16  50k x 256   } t2 (100k x 256 bf16) spans both
    //   [179.2M,204.8M)  tmp bf16      50k x 256   }
    //   [204.8M, ...)    starts/dtf/gmean/gvar/gpool (~0.8 MB)
    const size_t H_BYTES = (size_t)NN * HIDC * 2;
    const size_t AGG_BYTES = (size_t)NN * HIDC * 4;
    const size_t CH_BYTES = (size_t)50000 * HIDC * 2;
    char* ws = (char*)d_ws;
    bfu* hbuf = (bfu*)ws;
    float* aggb = (float*)(ws + H_BYTES);
    bfu* e_buf = (bfu*)(ws + H_BYTES + AGG_BYTES);
    bfu* tmp = (bfu*)(ws + H_BYTES + AGG_BYTES + CH_BYTES);
    bfu* t2 = e_buf;
    char* small = ws + H_BYTES + AGG_BYTES + 2 * CH_BYTES;
    int* starts = (int*)small;
    int* dtf = (int*)(small + 2048);
    float* gmean = (float*)(small + 4096);
    float* gvar = gmean + NG * HIDC;
    float* gpool = gvar + NG * HIDC;

    k_detect<<<1, 64, 0, stream>>>((const unsigned int*)ngamma, dtf);
    k_sent<<<1, 256, 0, stream>>>(d_out, dtf);          // background sentinel 42
    k_starts<<<1, 512, 0, stream>>>(batch, starts);
    k_embed<<<(NN * 64 + 255) / 256, 256, 0, stream>>>(x, node_emb_W, hbuf, dtf);
    k_mark<<<1, 64, 0, stream>>>(d_out, dtf, 50.0f);

    const int CH = 50000;
    dim3 gC((CH + BM - 1) / BM, 4), gN((NN + BM - 1) / BM, 4);
    const int aggN4 = NN * HIDC / 4;

    for (int l = 0; l < 3; ++l) {
        k_zero<<<(aggN4 + 255) / 256, 256, 0, stream>>>(aggb, aggN4);
        for (int c = 0; c < 8; ++c) {
            long atOff = (long)c * CH * 4;
            k_gemm<<<gC, 256, 0, stream>>>(
                nullptr, nullptr, eattr, atOff, edge_emb_W, edge_emb_b,
                nullptr, 0, emlp_W1, 0, emlp_b1, 0, nullptr, tmp, CH,
                1, 1, 0, dtf);
            if (l == 0 && c == 0) k_mark<<<1, 64, 0, stream>>>(d_out, dtf, 60.0f);
            k_gemm<<<gC, 256, 0, stream>>>(
                tmp, nullptr, eattr, atOff, nullptr, nullptr,
                nullptr, 0, emlp_W2, 0, emlp_b2, 0, struct_scale, e_buf, CH,
                0, 0, 1, dtf);
            k_scatter<<<(CH * 64 + 255) / 256, 256, 0, stream>>>(
                hbuf, e_buf, ei, aggb, c * CH, CH);
            if (l == 0 && c == 0) k_mark<<<1, 64, 0, stream>>>(d_out, dtf, 70.0f);
        }
        k_gemm<<<gN, 256, 0, stream>>>(
            hbuf, aggb, nullptr, 0, nullptr, nullptr,
            conv_eps, l, conv_W1, (long)l * HIDC * HIDC, conv_b1, (long)l * HIDC,
            nullptr, t2, NN, 2, 1, 0, dtf);
        k_gemm<<<gN, 256, 0, stream>>>(
            t2, nullptr, nullptr, 0, nullptr, nullptr,
            nullptr, 0, conv_W2, (long)l * HIDC * HIDC, conv_b2, (long)l * HIDC,
            nullptr, hbuf, NN, 0, 0, 0, dtf);
        if (l == 0) k_mark<<<1, 64, 0, stream>>>(d_out, dtf, 80.0f);
        k_stats<<<NG, HIDC, 0, stream>>>(hbuf, starts, nalpha, (long)l * HIDC,
                                         gmean, gvar, dtf);
        k_norm<<<(NN * 64 + 255) / 256, 256, 0, stream>>>(
            hbuf, batch, gmean, gvar, ngamma, nbeta, nalpha, (long)l * HIDC, dtf);
        if (l == 0) k_mark<<<1, 64, 0, stream>>>(d_out, dtf, 90.0f);
    }
    k_mark<<<1, 64, 0, stream>>>(d_out, dtf, 100.0f);

    k_pool<<<NG, HIDC, 0, stream>>>(hbuf, starts, gpool);
    k_mark<<<1, 64, 0, stream>>>(d_out, dtf, 110.0f);
    k_head<<<NG, 256, 0, stream>>>(gpool, mean_bio, head_W1, head_b1,
                                   head_W2, head_b2, d_out, dtf);
}

// Round 8
// 6592.276 us; speedup vs baseline: 1.6809x; 1.6809x over previous
//
#include <hip/hip_runtime.h>
#include <cstddef>

#define NN 100000
#define NE 400000
#define NG 256
#define HIDC 256
#define EPSN 1e-5f

typedef unsigned short bfu;  // bf16 bits
using short8 = __attribute__((ext_vector_type(8))) short;   // 8 bf16 (4 VGPRs)
using f32x4  = __attribute__((ext_vector_type(4))) float;   // MFMA acc

__device__ __forceinline__ float bf2f(bfu b) {
    union { unsigned int u; float f; } v; v.u = ((unsigned int)b) << 16; return v.f;
}
__device__ __forceinline__ bfu f2bf(float f) {
    union { float f; unsigned int u; } v; v.f = f;
    unsigned int r = v.u + 0x7FFFu + ((v.u >> 16) & 1u);
    return (bfu)(r >> 16);
}
// dual-dtype helpers: bf=1 -> bf16 storage, bf=0 -> fp32 storage
__device__ __forceinline__ float4 ld4(const void* p, size_t i, int bf) {
    if (bf) {
        ushort4 u = *(const ushort4*)((const bfu*)p + i);
        return make_float4(bf2f(u.x), bf2f(u.y), bf2f(u.z), bf2f(u.w));
    }
    return *(const float4*)((const float*)p + i);
}
__device__ __forceinline__ float ld1(const void* p, size_t i, int bf) {
    return bf ? bf2f(((const bfu*)p)[i]) : ((const float*)p)[i];
}
__device__ __forceinline__ void st1(void* p, size_t i, float v, int bf) {
    if (bf) ((bfu*)p)[i] = f2bf(v); else ((float*)p)[i] = v;
}

// ---------------- dtype detect: norm_gamma == ones ----------------
__global__ void k_detect(const unsigned int* __restrict__ g, int* __restrict__ flag) {
    if (threadIdx.x == 0)
        flag[0] = (g[0] == 0x3F800000u) ? 0 : 1;
}

// ---------------- graph starts (batch sorted) ----------------
__global__ void k_starts(const int* __restrict__ batch, int* __restrict__ starts) {
    int g = threadIdx.x;
    if (g > NG) return;
    if (g == NG) { starts[NG] = NN; return; }
    int lo = 0, hi = NN;
    while (lo < hi) { int mid = (lo + hi) >> 1; if (batch[mid] < g) lo = mid + 1; else hi = mid; }
    starts[g] = lo;
}

// ---------------- zero fill ----------------
__global__ void k_zero(float* __restrict__ p, int n4) {
    int i = blockIdx.x * blockDim.x + threadIdx.x;
    if (i < n4) ((float4*)p)[i] = make_float4(0.f, 0.f, 0.f, 0.f);
}

// ---------------- weight transpose to bf16: Wt[n][k] <- W[k][n] ----------------
__global__ void k_wt(const void* __restrict__ W, long wOff, bfu* __restrict__ Wt,
                     const int* __restrict__ dtf) {
    int i = blockIdx.x * blockDim.x + threadIdx.x;   // 65536
    if (i >= HIDC * HIDC) return;
    int n = i >> 8, k = i & 255;
    Wt[i] = f2bf(ld1(W, (size_t)wOff + (size_t)k * HIDC + n, *dtf));
}

// ---------------- node embedding gather ----------------
__global__ void k_embed(const int* __restrict__ x, const void* __restrict__ W,
                        bfu* __restrict__ h, const int* __restrict__ dtf) {
    int tid = blockIdx.x * blockDim.x + threadIdx.x;
    if (tid >= NN * 64) return;
    int bf = *dtf;
    int n = tid >> 6, q = (tid & 63) << 2;
    int xv = x[n]; if ((unsigned)xv >= 8u) xv = 0;
    float4 v = ld4(W, (size_t)xv * HIDC + q, bf);
    ushort4 o; o.x = f2bf(v.x); o.y = f2bf(v.y); o.z = f2bf(v.z); o.w = f2bf(v.w);
    *(ushort4*)(h + (size_t)n * HIDC + q) = o;
}

// ---------------- scatter: agg[dst] += relu(h[src] + e) ----------------
__global__ void k_scatter(const bfu* __restrict__ h, const bfu* __restrict__ e,
                          const int* __restrict__ ei, float* __restrict__ agg,
                          int e0, int ecnt) {
    int tid = blockIdx.x * blockDim.x + threadIdx.x;
    if (tid >= ecnt * 64) return;
    int eid = tid >> 6, q = (tid & 63) << 2;
    int ge = e0 + eid;
    int s = ei[ge], d = ei[NE + ge];
    if ((unsigned)s >= (unsigned)NN || (unsigned)d >= (unsigned)NN) return;
    ushort4 hu = *(const ushort4*)(h + (size_t)s * HIDC + q);
    ushort4 eu = *(const ushort4*)(e + (size_t)eid * HIDC + q);
    float4 m;
    m.x = fmaxf(bf2f(hu.x) + bf2f(eu.x), 0.f);
    m.y = fmaxf(bf2f(hu.y) + bf2f(eu.y), 0.f);
    m.z = fmaxf(bf2f(hu.z) + bf2f(eu.z), 0.f);
    m.w = fmaxf(bf2f(hu.w) + bf2f(eu.w), 0.f);
    float* ap = agg + (size_t)d * HIDC + q;
    atomicAdd(ap + 0, m.x); atomicAdd(ap + 1, m.y);
    atomicAdd(ap + 2, m.z); atomicAdd(ap + 3, m.w);
}

// ---------------- MFMA GEMM: C_bf16[M x 256] = A @ W + bias ----------------
// Block = 64 rows x all 256 cols (no A re-read). 4 waves; wave w owns cols
// [64w,64w+64) = 4x4 tiles of 16x16. Wt is pre-transposed bf16 [256n][256k].
// amode 0: A plain bf16.  amode 1: fused edge-emb.  amode 2: (1+eps)h + agg.
__global__ __launch_bounds__(256)
void k_mgemm(const bfu* __restrict__ A, const float* __restrict__ A2,
             const void* __restrict__ attrs, long atOff,
             const void* __restrict__ Wemb, const void* __restrict__ bemb,
             const void* __restrict__ eps, int epsIdx,
             const bfu* __restrict__ Wt,
             const void* __restrict__ bias, long bOff,
             const void* __restrict__ scalep,
             bfu* __restrict__ C, int M,
             int amode, int relu, int scale, const int* __restrict__ dtf) {
    __shared__ bfu As[64][40];
    __shared__ bfu Bs[256][40];
    const int bf = *dtf;
    const int tid = threadIdx.x;
    const int wave = tid >> 6, lane = tid & 63;
    const int lr = lane & 15, lq = lane >> 4;
    const int m0 = blockIdx.x * 64;
    f32x4 acc[4][4] = {};
    float epsv = 0.f;
    if (amode == 2) epsv = 1.0f + ld1(eps, epsIdx, bf);

    const int ar = tid >> 2;            // A-stage row 0..63
    const int ak = (tid & 3) << 3;      // A-stage k-offset {0,8,16,24}
    const int gmA = m0 + ar;

    for (int k0 = 0; k0 < 256; k0 += 32) {
        // ---- stage A tile (64x32 bf16) ----
        if (amode == 0) {
            uint4 u = make_uint4(0, 0, 0, 0);
            if (gmA < M) u = *(const uint4*)(A + (size_t)gmA * HIDC + k0 + ak);
            *(uint4*)(&As[ar][ak]) = u;
        } else if (amode == 2) {
            ushort4 h0 = {0,0,0,0}, h1 = {0,0,0,0};
            float4 g0 = make_float4(0,0,0,0), g1 = make_float4(0,0,0,0);
            if (gmA < M) {
                h0 = *(const ushort4*)(A + (size_t)gmA * HIDC + k0 + ak);
                h1 = *(const ushort4*)(A + (size_t)gmA * HIDC + k0 + ak + 4);
                g0 = *(const float4*)(A2 + (size_t)gmA * HIDC + k0 + ak);
                g1 = *(const float4*)(A2 + (size_t)gmA * HIDC + k0 + ak + 4);
            }
            ushort4 o0, o1;
            o0.x = f2bf(epsv * bf2f(h0.x) + g0.x); o0.y = f2bf(epsv * bf2f(h0.y) + g0.y);
            o0.z = f2bf(epsv * bf2f(h0.z) + g0.z); o0.w = f2bf(epsv * bf2f(h0.w) + g0.w);
            o1.x = f2bf(epsv * bf2f(h1.x) + g1.x); o1.y = f2bf(epsv * bf2f(h1.y) + g1.y);
            o1.z = f2bf(epsv * bf2f(h1.z) + g1.z); o1.w = f2bf(epsv * bf2f(h1.w) + g1.w);
            *(ushort4*)(&As[ar][ak])     = o0;
            *(ushort4*)(&As[ar][ak + 4]) = o1;
        } else {  // amode 1: fused edge embedding
            float v0=0,v1=0,v2=0,v3=0,v4=0,v5=0,v6=0,v7=0;
            if (gmA < M) {
                float aa[4];
                aa[0] = ld1(attrs, (size_t)atOff + (size_t)gmA * 4 + 0, bf);
                aa[1] = ld1(attrs, (size_t)atOff + (size_t)gmA * 4 + 1, bf);
                aa[2] = ld1(attrs, (size_t)atOff + (size_t)gmA * 4 + 2, bf);
                aa[3] = ld1(attrs, (size_t)atOff + (size_t)gmA * 4 + 3, bf);
                float4 c0 = ld4(bemb, k0 + ak, bf);
                float4 c1 = ld4(bemb, k0 + ak + 4, bf);
                v0=c0.x; v1=c0.y; v2=c0.z; v3=c0.w; v4=c1.x; v5=c1.y; v6=c1.z; v7=c1.w;
#pragma unroll
                for (int j = 0; j < 4; ++j) {
                    float4 w0 = ld4(Wemb, (size_t)j * HIDC + k0 + ak, bf);
                    float4 w1 = ld4(Wemb, (size_t)j * HIDC + k0 + ak + 4, bf);
                    v0 += aa[j]*w0.x; v1 += aa[j]*w0.y; v2 += aa[j]*w0.z; v3 += aa[j]*w0.w;
                    v4 += aa[j]*w1.x; v5 += aa[j]*w1.y; v6 += aa[j]*w1.z; v7 += aa[j]*w1.w;
                }
            }
            ushort4 o0, o1;
            o0.x = f2bf(v0); o0.y = f2bf(v1); o0.z = f2bf(v2); o0.w = f2bf(v3);
            o1.x = f2bf(v4); o1.y = f2bf(v5); o1.z = f2bf(v6); o1.w = f2bf(v7);
            *(ushort4*)(&As[ar][ak])     = o0;
            *(ushort4*)(&As[ar][ak + 4]) = o1;
        }
        // ---- stage B tile (256 cols x 32 k) from Wt[n][k] ----
#pragma unroll
        for (int r = 0; r < 4; ++r) {
            int idx = tid + (r << 8);
            int n = idx >> 2;
            int kk = (idx & 3) << 3;
            *(uint4*)(&Bs[n][kk]) = *(const uint4*)(Wt + (size_t)n * HIDC + k0 + kk);
        }
        __syncthreads();
        // ---- fragments + MFMA ----
        short8 fa[4], fb[4];
#pragma unroll
        for (int r = 0; r < 4; ++r)
            fa[r] = *(const short8*)(&As[r * 16 + lr][lq * 8]);
#pragma unroll
        for (int t = 0; t < 4; ++t)
            fb[t] = *(const short8*)(&Bs[wave * 64 + t * 16 + lr][lq * 8]);
#pragma unroll
        for (int r = 0; r < 4; ++r)
#pragma unroll
            for (int t = 0; t < 4; ++t)
                acc[r][t] = __builtin_amdgcn_mfma_f32_16x16x32_bf16(
                    fa[r], fb[t], acc[r][t], 0, 0, 0);
        __syncthreads();
    }

    // ---- epilogue: C row = m0 + r*16 + lq*4 + i, col = wave*64 + t*16 + lr ----
    float bv[4];
#pragma unroll
    for (int t = 0; t < 4; ++t) bv[t] = ld1(bias, (size_t)bOff + wave * 64 + t * 16 + lr, bf);
    float scv = scale ? ld1(scalep, 0, bf) : 1.0f;
#pragma unroll
    for (int r = 0; r < 4; ++r) {
#pragma unroll
        for (int i = 0; i < 4; ++i) {
            int gm = m0 + r * 16 + lq * 4 + i;
            if (gm >= M) continue;
            float rs = 1.0f;
            if (scale && ld1(attrs, (size_t)atOff + (size_t)gm * 4 + 1, bf) > 0.f) rs = scv;
#pragma unroll
            for (int t = 0; t < 4; ++t) {
                float o = acc[r][t][i] + bv[t];
                if (relu) o = fmaxf(o, 0.f);
                o *= rs;
                C[(size_t)gm * HIDC + wave * 64 + t * 16 + lr] = f2bf(o);
            }
        }
    }
}

// ---------------- GraphNorm stats ----------------
__global__ void k_stats(const bfu* __restrict__ h, const int* __restrict__ starts,
                        const void* __restrict__ alpha, long aOff,
                        float* __restrict__ gmean, float* __restrict__ gvar,
                        const int* __restrict__ dtf) {
    int bf = *dtf;
    int g = blockIdx.x, c = threadIdx.x;
    int s = starts[g], t = starts[g + 1];
    float sum = 0.f, sum2 = 0.f;
    for (int n = s; n < t; ++n) {
        float v = bf2f(h[(size_t)n * HIDC + c]);
        sum += v; sum2 += v * v;
    }
    int cn = t - s; if (cn < 1) cn = 1;
    float cnt = (float)cn;
    float m = sum / cnt;
    float a = ld1(alpha, (size_t)aOff + c, bf);
    float var = sum2 / cnt - (2.f * a - a * a) * m * m;
    gmean[g * HIDC + c] = m;
    gvar[g * HIDC + c] = fmaxf(var, 0.f);
}

// ---------------- GraphNorm apply ----------------
__global__ void k_norm(bfu* __restrict__ h, const int* __restrict__ batch,
                       const float* __restrict__ gmean, const float* __restrict__ gvar,
                       const void* __restrict__ gamma, const void* __restrict__ beta,
                       const void* __restrict__ alpha, long pOff,
                       const int* __restrict__ dtf) {
    int tid = blockIdx.x * blockDim.x + threadIdx.x;
    if (tid >= NN * 64) return;
    int bf = *dtf;
    int n = tid >> 6, q = (tid & 63) << 2;
    int g = batch[n]; if ((unsigned)g >= (unsigned)NG) g = 0;
    ushort4 hu = *(ushort4*)(h + (size_t)n * HIDC + q);
    const float4 mv = *(const float4*)(gmean + g * HIDC + q);
    const float4 vv = *(const float4*)(gvar + g * HIDC + q);
    float4 ga = ld4(gamma, (size_t)pOff + q, bf);
    float4 be = ld4(beta, (size_t)pOff + q, bf);
    float4 al = ld4(alpha, (size_t)pOff + q, bf);
    float4 v;
    v.x = ga.x * (bf2f(hu.x) - al.x * mv.x) * rsqrtf(vv.x + EPSN) + be.x;
    v.y = ga.y * (bf2f(hu.y) - al.y * mv.y) * rsqrtf(vv.y + EPSN) + be.y;
    v.z = ga.z * (bf2f(hu.z) - al.z * mv.z) * rsqrtf(vv.z + EPSN) + be.z;
    v.w = ga.w * (bf2f(hu.w) - al.w * mv.w) * rsqrtf(vv.w + EPSN) + be.w;
    ushort4 ov; ov.x = f2bf(v.x); ov.y = f2bf(v.y); ov.z = f2bf(v.z); ov.w = f2bf(v.w);
    *(ushort4*)(h + (size_t)n * HIDC + q) = ov;
}

// ---------------- global mean pool ----------------
__global__ void k_pool(const bfu* __restrict__ h, const int* __restrict__ starts,
                       float* __restrict__ g) {
    int gb = blockIdx.x, c = threadIdx.x;
    int s = starts[gb], t = starts[gb + 1];
    float sum = 0.f;
    for (int n = s; n < t; ++n) sum += bf2f(h[(size_t)n * HIDC + c]);
    int cn = t - s; if (cn < 1) cn = 1;
    g[gb * HIDC + c] = sum / (float)cn;
}

// ---------------- head MLP ----------------
__global__ void k_head(const float* __restrict__ g, const void* __restrict__ bio,
                       const void* __restrict__ W1, const void* __restrict__ b1,
                       const void* __restrict__ W2, const void* __restrict__ b2,
                       void* __restrict__ out, const int* __restrict__ dtf) {
    __shared__ float comb[768];
    __shared__ float red[256];
    __shared__ int nanf;
    int bf = *dtf;
    int gb = blockIdx.x, t = threadIdx.x;
    if (t == 0) nanf = 0;
    comb[t] = g[gb * HIDC + t];
    comb[256 + t] = ld1(bio, t, bf);
    comb[512 + t] = ld1(bio, 256 + t, bf);
    __syncthreads();
    float acc = ld1(b1, t, bf);
    for (int k = 0; k < 768; ++k) acc += comb[k] * ld1(W1, (size_t)k * HIDC + t, bf);
    if (isnan(acc) || isinf(acc)) nanf = 1;
    float hid = fmaxf(acc, 0.f);
    red[t] = hid * ld1(W2, t, bf);
    __syncthreads();
    for (int off = 128; off > 0; off >>= 1) {
        if (t < off) red[t] += red[t + off];
        __syncthreads();
    }
    if (t == 0) {
        float r = red[0] + ld1(b2, 0, bf);
        if (nanf || isnan(r)) r = 999.0f;
        st1(out, gb, r, bf);
    }
}

extern "C" void kernel_launch(void* const* d_in, const int* in_sizes, int n_in,
                              void* d_out, int out_size, void* d_ws, size_t ws_size,
                              hipStream_t stream) {
    const int* x = (const int*)d_in[0];
    const int* ei = (const int*)d_in[1];
    const void* eattr = d_in[2];
    const int* batch = (const int*)d_in[3];
    const void* node_emb_W = d_in[4];
    const void* edge_emb_W = d_in[5];
    const void* edge_emb_b = d_in[6];
    const void* emlp_W1 = d_in[7];
    const void* emlp_b1 = d_in[8];
    const void* emlp_W2 = d_in[9];
    const void* emlp_b2 = d_in[10];
    const void* struct_scale = d_in[11];
    const void* conv_W1 = d_in[12];
    const void* conv_b1 = d_in[13];
    const void* conv_W2 = d_in[14];
    const void* conv_b2 = d_in[15];
    const void* conv_eps = d_in[16];
    const void* ngamma = d_in[17];
    const void* nbeta = d_in[18];
    const void* nalpha = d_in[19];
    const void* mean_bio = d_in[20];
    const void* head_W1 = d_in[21];
    const void* head_b1 = d_in[22];
    const void* head_W2 = d_in[23];
    const void* head_b2 = d_in[24];
    (void)in_sizes; (void)n_in; (void)out_size;

    const size_t H_B   = (size_t)NN * HIDC * 2;    // 51.2 MB
    const size_t AGG_B = (size_t)NN * HIDC * 4;    // 102.4 MB
    const size_t E_B   = (size_t)NE * HIDC * 2;    // 204.8 MB
    const size_t WT_B  = 8 * 65536 * 2;            // 1 MB
    const size_t SM_B  = 1000000;

    // Tiering on actual ws_size:
    //  FAST: e stored once (X=51.2 for tmp/t2)       -> 412.6 MB
    //  MID : per-layer recompute, 100k chunks (X=102.4) -> 258.0 MB
    //  LOW : per-layer recompute,  50k chunks (X=51.2)  -> 206.8 MB (r7-proven)
    int tier;
    if (ws_size >= E_B + H_B + AGG_B + 51200000 + WT_B + SM_B) tier = 2;
    else if (ws_size >= H_B + AGG_B + 102400000 + WT_B + SM_B) tier = 1;
    else tier = 0;

    char* p = (char*)d_ws;
    bfu* e_full = nullptr;
    if (tier == 2) { e_full = (bfu*)p; p += E_B; }
    bfu* hbuf = (bfu*)p; p += H_B;
    float* aggb = (float*)p; p += AGG_B;
    bfu* xbuf = (bfu*)p; p += (tier == 1) ? 102400000 : 51200000;
    bfu* wt = (bfu*)p; p += WT_B;
    char* small = p;
    int* starts = (int*)small;
    int* dtf = (int*)(small + 2048);
    float* gmean = (float*)(small + 4096);
    float* gvar = gmean + NG * HIDC;
    float* gpool = gvar + NG * HIDC;

    k_detect<<<1, 64, 0, stream>>>((const unsigned int*)ngamma, dtf);
    k_starts<<<1, 512, 0, stream>>>(batch, starts);
    k_embed<<<(NN * 64 + 255) / 256, 256, 0, stream>>>(x, node_emb_W, hbuf, dtf);

    // Pre-transpose all 256x256 GEMM weights to bf16 Wt[n][k]:
    // slot 0 = emlp_W1, 1 = emlp_W2, 2+l = conv_W1[l], 5+l = conv_W2[l]
    k_wt<<<256, 256, 0, stream>>>(emlp_W1, 0, wt, dtf);
    k_wt<<<256, 256, 0, stream>>>(emlp_W2, 0, wt + 65536, dtf);
    for (int l = 0; l < 3; ++l) {
        k_wt<<<256, 256, 0, stream>>>(conv_W1, (long)l * HIDC * HIDC, wt + (2 + l) * 65536, dtf);
        k_wt<<<256, 256, 0, stream>>>(conv_W2, (long)l * HIDC * HIDC, wt + (5 + l) * 65536, dtf);
    }

    const int aggN4 = NN * HIDC / 4;

    if (tier == 2) {
        // edge MLP once: 4 chunks of 100k, tmp = xbuf
        const int CH = 100000;
        dim3 gC((CH + 63) / 64);
        for (int c = 0; c < 4; ++c) {
            long atOff = (long)c * CH * 4;
            k_mgemm<<<gC, 256, 0, stream>>>(
                nullptr, nullptr, eattr, atOff, edge_emb_W, edge_emb_b,
                nullptr, 0, wt, emlp_b1, 0, nullptr, xbuf, CH, 1, 1, 0, dtf);
            k_mgemm<<<gC, 256, 0, stream>>>(
                xbuf, nullptr, eattr, atOff, nullptr, nullptr,
                nullptr, 0, wt + 65536, emlp_b2, 0, struct_scale,
                e_full + (size_t)c * CH * HIDC, CH, 0, 0, 1, dtf);
        }
    }

    const int CH = (tier == 1) ? 100000 : 50000;
    const int NCH = NE / CH;
    dim3 gC((CH + 63) / 64), gN((NN + 63) / 64);
    bfu* echunk = xbuf;
    bfu* tmp = xbuf + (size_t)CH * HIDC;

    for (int l = 0; l < 3; ++l) {
        k_zero<<<(aggN4 + 255) / 256, 256, 0, stream>>>(aggb, aggN4);
        if (tier == 2) {
            k_scatter<<<(NE * 64 + 255) / 256, 256, 0, stream>>>(
                hbuf, e_full, ei, aggb, 0, NE);
        } else {
            for (int c = 0; c < NCH; ++c) {
                long atOff = (long)c * CH * 4;
                k_mgemm<<<gC, 256, 0, stream>>>(
                    nullptr, nullptr, eattr, atOff, edge_emb_W, edge_emb_b,
                    nullptr, 0, wt, emlp_b1, 0, nullptr, tmp, CH, 1, 1, 0, dtf);
                k_mgemm<<<gC, 256, 0, stream>>>(
                    tmp, nullptr, eattr, atOff, nullptr, nullptr,
                    nullptr, 0, wt + 65536, emlp_b2, 0, struct_scale,
                    echunk, CH, 0, 0, 1, dtf);
                k_scatter<<<(CH * 64 + 255) / 256, 256, 0, stream>>>(
                    hbuf, echunk, ei, aggb, c * CH, CH);
            }
        }
        // t2 = relu(((1+eps)h + agg) @ convW1 + b1)   (t2 reuses xbuf)
        k_mgemm<<<gN, 256, 0, stream>>>(
            hbuf, aggb, nullptr, 0, nullptr, nullptr,
            conv_eps, l, wt + (2 + l) * 65536, conv_b1, (long)l * HIDC,
            nullptr, xbuf, NN, 2, 1, 0, dtf);
        // h = t2 @ convW2 + b2
        k_mgemm<<<gN, 256, 0, stream>>>(
            xbuf, nullptr, nullptr, 0, nullptr, nullptr,
            nullptr, 0, wt + (5 + l) * 65536, conv_b2, (long)l * HIDC,
            nullptr, hbuf, NN, 0, 0, 0, dtf);
        k_stats<<<NG, HIDC, 0, stream>>>(hbuf, starts, nalpha, (long)l * HIDC,
                                         gmean, gvar, dtf);
        k_norm<<<(NN * 64 + 255) / 256, 256, 0, stream>>>(
            hbuf, batch, gmean, gvar, ngamma, nbeta, nalpha, (long)l * HIDC, dtf);
    }

    k_pool<<<NG, HIDC, 0, stream>>>(hbuf, starts, gpool);
    k_head<<<NG, 256, 0, stream>>>(gpool, mean_bio, head_W1, head_b1,
                                   head_W2, head_b2, d_out, dtf);
}